// Round 7
// baseline (206.214 us; speedup 1.0000x reference)
//
#include <hip/hip_runtime.h>

#define ROWS 4
#define N 4096
#define BATCH 8192
#define PAD_STRIDE 264              // 256 + 8 words: breaks power-of-2 bank stride
#define BUF_WORDS (16 * PAD_STRIDE) // 4224 floats = 16896 B single transpose buffer

typedef float v4f __attribute__((ext_vector_type(4)));

__device__ __forceinline__ void layer_compute(float (&v)[ROWS][16],
                                              const float4 (&w)[8],
                                              const int bit) {
    const int d = 1 << bit;
    #pragma unroll
    for (int r = 0; r < ROWS; ++r) {
        #pragma unroll
        for (int pc = 0; pc < 8; ++pc) {
            const int lo = ((pc >> bit) << (bit + 1)) | (pc & (d - 1));
            const int hi = lo + d;
            const float top = v[r][lo];
            const float bot = v[r][hi];
            v[r][lo] = w[pc].x * top + w[pc].y * bot;
            v[r][hi] = w[pc].z * top + w[pc].w * bot;
        }
    }
}

// No __launch_bounds__: the twiddle software pipeline needs 64 data + 64
// twiddle = ~128 live VGPRs. R4/R5 proved forcing caps below the live state
// spills to scratch (FETCH/WRITE blow up 2-4x). We deliberately trade waves
// (9 -> ~6/CU) for ILP: each layer's 8 float4 twiddle loads are issued one
// full layer ahead (w0/w1 ping-pong), hiding the ~300cy L2 latency that R6's
// counters implicate as the dominant per-wave stall (96 serial-ish L2 loads).
__global__
void butterfly_kernel(const float* __restrict__ x,
                      const float* __restrict__ tw,
                      float* __restrict__ out) {
    __shared__ float lds[BUF_WORDS];
    const int t   = threadIdx.x;
    const int thi = t >> 4;   // t / 16
    const int tlo = t & 15;   // t % 16
    const int row0 = blockIdx.x * ROWS;

    const float4* tw4 = (const float4*)tw;

    // Twiddle load helpers (normal, cacheable loads: 384KB table is L2/L3
    // resident and shared across all blocks — do NOT mark nontemporal).
    auto ldA = [&](int l, float4 (&w)[8]) {
        #pragma unroll
        for (int pc = 0; pc < 8; ++pc) w[pc] = tw4[l * 2048 + pc * 256 + t];
    };
    auto ldB = [&](int l, float4 (&w)[8]) {
        #pragma unroll
        for (int pc = 0; pc < 8; ++pc) w[pc] = tw4[l * 2048 + thi * 128 + pc * 16 + tlo];
    };
    auto ldC = [&](int l, float4 (&w)[8]) {
        #pragma unroll
        for (int pc = 0; pc < 8; ++pc) w[pc] = tw4[l * 2048 + thi * 128 + tlo * 8 + pc];
    };

    float v[ROWS][16];

    // ---- Load: v[r][a] = x[(row0+r)*N + a*256 + t]  (coalesced dword per a)
    #pragma unroll
    for (int r = 0; r < ROWS; ++r) {
        const float* xr = x + (size_t)(row0 + r) * N + t;
        #pragma unroll
        for (int a = 0; a < 16; ++a)
            v[r][a] = __builtin_nontemporal_load(xr + a * 256);
    }

    float4 w0[8], w1[8];

    // ---- Stage A: layers 0..3 (strides 2048,1024,512,256) — pair dim = a.
    // 1-layer-deep pipeline: load l+1 while computing l.
    ldA(0, w0);
    ldA(1, w1);  layer_compute(v, w0, 3);
    ldA(2, w0);  layer_compute(v, w1, 2);
    ldA(3, w1);  layer_compute(v, w0, 1);
    ldB(4, w0);  layer_compute(v, w1, 0);   // prefetch stage-B layer 4; lands during transpose

    // ---- Transpose A->B: thread t held (b=thi,c=tlo) all-a; becomes (a=thi,c=tlo) all-b
    #pragma unroll
    for (int r = 0; r < ROWS; ++r) {
        #pragma unroll
        for (int a = 0; a < 16; ++a)
            lds[a * PAD_STRIDE + t] = v[r][a];      // stride-1 across lanes: conflict-free
        __syncthreads();
        #pragma unroll
        for (int b = 0; b < 16; ++b)                // 2-way conflict (free)
            v[r][b] = lds[thi * PAD_STRIDE + b * 16 + tlo];
        __syncthreads();
    }

    // ---- Stage B: layers 4..7 (strides 128,64,32,16) — pair dim = b
    ldB(5, w1);  layer_compute(v, w0, 3);
    ldB(6, w0);  layer_compute(v, w1, 2);
    ldB(7, w1);  layer_compute(v, w0, 1);
    ldC(8, w0);  layer_compute(v, w1, 0);   // prefetch stage-C layer 8

    // ---- Transpose B->C: thread becomes (a=thi,b=tlo) holding contiguous c
    #pragma unroll
    for (int r = 0; r < ROWS; ++r) {
        #pragma unroll
        for (int b = 0; b < 16; ++b)                // 2-way conflict (free)
            lds[thi * PAD_STRIDE + b * 16 + tlo] = v[r][b];
        __syncthreads();
        const float* bp = &lds[thi * PAD_STRIDE + tlo * 16];
        #pragma unroll
        for (int q = 0; q < 4; ++q) {               // contiguous b128 reads
            v4f c4 = *(const v4f*)(bp + 4 * q);
            v[r][4 * q + 0] = c4.x;
            v[r][4 * q + 1] = c4.y;
            v[r][4 * q + 2] = c4.z;
            v[r][4 * q + 3] = c4.w;
        }
        if (r != ROWS - 1) __syncthreads();
    }

    // ---- Stage C: layers 8..11 (strides 8,4,2,1) — pair dim = c
    ldC(9,  w1);  layer_compute(v, w0, 3);
    ldC(10, w0);  layer_compute(v, w1, 2);
    ldC(11, w1);  layer_compute(v, w0, 1);
                  layer_compute(v, w1, 0);

    // ---- Store: thread holds elements [16t, 16t+16) of each row — 4x float4.
    // Plain write-back stores: L2 merges the 64B-strided 16B chunks into full
    // lines (nt hint here caused 2.6x write amplification — R2 counters).
    #pragma unroll
    for (int r = 0; r < ROWS; ++r) {
        float* orow = out + (size_t)(row0 + r) * N + 16 * t;
        #pragma unroll
        for (int q = 0; q < 4; ++q) {
            v4f s4;
            s4.x = v[r][4 * q + 0];
            s4.y = v[r][4 * q + 1];
            s4.z = v[r][4 * q + 2];
            s4.w = v[r][4 * q + 3];
            *(v4f*)(orow + 4 * q) = s4;
        }
    }
}

extern "C" void kernel_launch(void* const* d_in, const int* in_sizes, int n_in,
                              void* d_out, int out_size, void* d_ws, size_t ws_size,
                              hipStream_t stream) {
    const float* x  = (const float*)d_in[0];
    const float* tw = (const float*)d_in[1];
    float* out      = (float*)d_out;
    dim3 grid(BATCH / ROWS);
    dim3 block(256);
    hipLaunchKernelGGL(butterfly_kernel, grid, block, 0, stream, x, tw, out);
}

// Round 8
// 111.777 us; speedup vs baseline: 1.8449x; 1.8449x over previous
//
#include <hip/hip_runtime.h>

#define ROWS 4
#define N 4096
#define BATCH 8192
#define PAD_STRIDE 264              // 256 + 8 words: breaks power-of-2 bank stride
#define BUF_WORDS (16 * PAD_STRIDE) // 4224 floats = 16896 B single transpose buffer

typedef float v4f __attribute__((ext_vector_type(4)));

// Half-layer butterfly: pcs [pcb, pcb+4) with twiddles in s[0..3].
__device__ __forceinline__ void half_layer(float (&v)[ROWS][16],
                                           const float4 (&s)[4],
                                           const int bit, const int pcb) {
    const int d = 1 << bit;
    #pragma unroll
    for (int i = 0; i < 4; ++i) {
        const int pc = pcb + i;
        const int lo = ((pc >> bit) << (bit + 1)) | (pc & (d - 1));
        const int hi = lo + d;
        #pragma unroll
        for (int r = 0; r < ROWS; ++r) {
            const float top = v[r][lo];
            const float bot = v[r][hi];
            v[r][lo] = s[i].x * top + s[i].y * bot;
            v[r][hi] = s[i].z * top + s[i].w * bot;
        }
    }
}

// launch_bounds(256,2): empirical VGPR cap on this toolchain is ~256/min_waves
// (R3/R5/R6/R7: arg3->84, arg4->64, arg5->48, none->64+spills). arg2 -> 128.
// Live state: 64 data + 48 twiddle (3 slots x 4 float4) + temps ~= 124 < 128.
// The 3-slot rotation gives ~1-layer prefetch depth, hiding the ~300-600cy
// L2 twiddle latency that R6's counters implicate as the dominant stall
// (12 serial load->compute exposures/wave). R7's 2x8-float4 banks needed
// ~140+ live and spilled at the default 64-reg cap.
__global__ __launch_bounds__(256, 2)
void butterfly_kernel(const float* __restrict__ x,
                      const float* __restrict__ tw,
                      float* __restrict__ out) {
    __shared__ float lds[BUF_WORDS];
    const int t   = threadIdx.x;
    const int thi = t >> 4;   // t / 16
    const int tlo = t & 15;   // t % 16
    const int row0 = blockIdx.x * ROWS;

    const float4* tw4 = (const float4*)tw;

    // Twiddle half-layer loaders (cacheable: 384KB table is L2/L3-shared).
    auto ld4A = [&](int l, int pcb, float4 (&s)[4]) {
        #pragma unroll
        for (int i = 0; i < 4; ++i) s[i] = tw4[l * 2048 + (pcb + i) * 256 + t];
    };
    auto ld4B = [&](int l, int pcb, float4 (&s)[4]) {
        #pragma unroll
        for (int i = 0; i < 4; ++i) s[i] = tw4[l * 2048 + thi * 128 + (pcb + i) * 16 + tlo];
    };
    auto ld4C = [&](int l, int pcb, float4 (&s)[4]) {
        #pragma unroll
        for (int i = 0; i < 4; ++i) s[i] = tw4[l * 2048 + thi * 128 + tlo * 8 + (pcb + i)];
    };

    float v[ROWS][16];

    // ---- Load: v[r][a] = x[(row0+r)*N + a*256 + t]  (coalesced dword per a)
    #pragma unroll
    for (int r = 0; r < ROWS; ++r) {
        const float* xr = x + (size_t)(row0 + r) * N + t;
        #pragma unroll
        for (int a = 0; a < 16; ++a)
            v[r][a] = __builtin_nontemporal_load(xr + a * 256);
    }

    float4 S0[4], S1[4], S2[4];

    // ---- Stage A: layers 0..3 (pair dim = a). 3-slot half-layer pipeline:
    // per layer: {load next.h0 -> freed slot; compute cur.h0;
    //             load next.h1 -> cur.h0's slot; compute cur.h1}
    ld4A(0, 0, S0); ld4A(0, 4, S1);
    ld4A(1, 0, S2); half_layer(v, S0, 3, 0); ld4A(1, 4, S0); half_layer(v, S1, 3, 4); // l=0
    ld4A(2, 0, S1); half_layer(v, S2, 2, 0); ld4A(2, 4, S2); half_layer(v, S0, 2, 4); // l=1
    ld4A(3, 0, S0); half_layer(v, S1, 1, 0); ld4A(3, 4, S1); half_layer(v, S2, 1, 4); // l=2
    ld4B(4, 0, S2); half_layer(v, S0, 0, 0); ld4B(4, 4, S0); half_layer(v, S1, 0, 4); // l=3; L4 flies over transpose

    // ---- Transpose A->B: thread t held (b=thi,c=tlo) all-a; becomes (a=thi,c=tlo) all-b
    #pragma unroll
    for (int r = 0; r < ROWS; ++r) {
        #pragma unroll
        for (int a = 0; a < 16; ++a)
            lds[a * PAD_STRIDE + t] = v[r][a];      // stride-1 across lanes: conflict-free
        __syncthreads();
        #pragma unroll
        for (int b = 0; b < 16; ++b)                // 2-way conflict (free)
            v[r][b] = lds[thi * PAD_STRIDE + b * 16 + tlo];
        __syncthreads();
    }

    // ---- Stage B: layers 4..7 (pair dim = b)
    ld4B(5, 0, S1); half_layer(v, S2, 3, 0); ld4B(5, 4, S2); half_layer(v, S0, 3, 4); // l=4
    ld4B(6, 0, S0); half_layer(v, S1, 2, 0); ld4B(6, 4, S1); half_layer(v, S2, 2, 4); // l=5
    ld4B(7, 0, S2); half_layer(v, S0, 1, 0); ld4B(7, 4, S0); half_layer(v, S1, 1, 4); // l=6
    ld4C(8, 0, S1); half_layer(v, S2, 0, 0); ld4C(8, 4, S2); half_layer(v, S0, 0, 4); // l=7; L8 flies over transpose

    // ---- Transpose B->C: thread becomes (a=thi,b=tlo) holding contiguous c
    #pragma unroll
    for (int r = 0; r < ROWS; ++r) {
        #pragma unroll
        for (int b = 0; b < 16; ++b)                // 2-way conflict (free)
            lds[thi * PAD_STRIDE + b * 16 + tlo] = v[r][b];
        __syncthreads();
        const float* bp = &lds[thi * PAD_STRIDE + tlo * 16];
        #pragma unroll
        for (int q = 0; q < 4; ++q) {               // contiguous b128 reads
            v4f c4 = *(const v4f*)(bp + 4 * q);
            v[r][4 * q + 0] = c4.x;
            v[r][4 * q + 1] = c4.y;
            v[r][4 * q + 2] = c4.z;
            v[r][4 * q + 3] = c4.w;
        }
        if (r != ROWS - 1) __syncthreads();
    }

    // ---- Stage C: layers 8..11 (pair dim = c)
    ld4C(9,  0, S0); half_layer(v, S1, 3, 0); ld4C(9,  4, S1); half_layer(v, S2, 3, 4); // l=8
    ld4C(10, 0, S2); half_layer(v, S0, 2, 0); ld4C(10, 4, S0); half_layer(v, S1, 2, 4); // l=9
    ld4C(11, 0, S1); half_layer(v, S2, 1, 0); ld4C(11, 4, S2); half_layer(v, S0, 1, 4); // l=10
                     half_layer(v, S1, 0, 0);                  half_layer(v, S2, 0, 4); // l=11

    // ---- Store: thread holds elements [16t, 16t+16) of each row — 4x float4.
    // Plain write-back stores: L2 merges the 64B-strided 16B chunks into full
    // lines (nt hint here caused 2.6x write amplification — R2 counters).
    #pragma unroll
    for (int r = 0; r < ROWS; ++r) {
        float* orow = out + (size_t)(row0 + r) * N + 16 * t;
        #pragma unroll
        for (int q = 0; q < 4; ++q) {
            v4f s4;
            s4.x = v[r][4 * q + 0];
            s4.y = v[r][4 * q + 1];
            s4.z = v[r][4 * q + 2];
            s4.w = v[r][4 * q + 3];
            *(v4f*)(orow + 4 * q) = s4;
        }
    }
}

extern "C" void kernel_launch(void* const* d_in, const int* in_sizes, int n_in,
                              void* d_out, int out_size, void* d_ws, size_t ws_size,
                              hipStream_t stream) {
    const float* x  = (const float*)d_in[0];
    const float* tw = (const float*)d_in[1];
    float* out      = (float*)d_out;
    dim3 grid(BATCH / ROWS);
    dim3 block(256);
    hipLaunchKernelGGL(butterfly_kernel, grid, block, 0, stream, x, tw, out);
}

// Round 9
// 77.414 us; speedup vs baseline: 2.6638x; 1.4439x over previous
//
#include <hip/hip_runtime.h>

#define ROWS 4
#define N 4096
#define BATCH 8192
#define PAD_STRIDE 264              // 256 + 8 words: breaks power-of-2 bank stride
#define BUF_WORDS (16 * PAD_STRIDE) // 4224 floats; also >= 4096 for flat store restage

typedef float v4f __attribute__((ext_vector_type(4)));

__device__ __forceinline__ void layer_compute(float (&v)[ROWS][16],
                                              const float4 (&w)[8],
                                              const int bit) {
    const int d = 1 << bit;
    #pragma unroll
    for (int pc = 0; pc < 8; ++pc) {
        const int lo = ((pc >> bit) << (bit + 1)) | (pc & (d - 1));
        const int hi = lo + d;
        #pragma unroll
        for (int r = 0; r < ROWS; ++r) {
            const float top = v[r][lo];
            const float bot = v[r][hi];
            v[r][lo] = w[pc].x * top + w[pc].y * bot;
            v[r][hi] = w[pc].z * top + w[pc].w * bot;
        }
    }
}

// ---- Prepass: permute twiddle layers 4..11 into lane-coalesced layout in d_ws.
// Main-kernel stage B needs w[pc]=old[l][a*128+pc*16+c] (a=thi,c=tlo); stage C
// needs old[l][a*128+b*8+pc]. Both become new[slot][pc*256 + t] so each load
// instruction reads 64 consecutive float4 (1KB contiguous per wave) instead of
// 64 scattered 16B sectors (the measured TA/L2 request-rate wall, R6/R8).
__global__ __launch_bounds__(256)
void permute_tw_kernel(const float* __restrict__ tw, float4* __restrict__ nws) {
    const int i = blockIdx.x * 256 + threadIdx.x;   // 0 .. 16383
    const int s  = i >> 11;                         // slot 0..7 -> layer 4+s
    const int j  = i & 2047;
    const int pc = j >> 8;
    const int a  = (j >> 4) & 15;
    const int cb = j & 15;
    const float4* tw4 = (const float4*)tw;
    const int src = (s < 4) ? (a * 128 + pc * 16 + cb)   // stage B layers 4..7
                            : (a * 128 + cb * 8 + pc);   // stage C layers 8..11
    nws[i] = tw4[(4 + s) * 2048 + src];
}

// ---- Main kernel (coalesced twiddles from nws + LDS-restaged stores)
__global__ __launch_bounds__(256, 3)
void butterfly_kernel(const float* __restrict__ x,
                      const float* __restrict__ tw,
                      const float4* __restrict__ nws,
                      float* __restrict__ out) {
    __shared__ float lds[BUF_WORDS];
    const int t   = threadIdx.x;
    const int thi = t >> 4;   // t / 16
    const int tlo = t & 15;   // t % 16
    const int row0 = blockIdx.x * ROWS;

    const float4* tw4 = (const float4*)tw;

    float v[ROWS][16];

    // ---- Load: v[r][a] = x[(row0+r)*N + a*256 + t]  (coalesced dword per a)
    #pragma unroll
    for (int r = 0; r < ROWS; ++r) {
        const float* xr = x + (size_t)(row0 + r) * N + t;
        #pragma unroll
        for (int a = 0; a < 16; ++a)
            v[r][a] = __builtin_nontemporal_load(xr + a * 256);
    }

    // ---- Stage A: layers 0..3 (pair dim = a); original layout already coalesced
    #pragma unroll
    for (int l = 0; l < 4; ++l) {
        float4 w[8];
        #pragma unroll
        for (int pc = 0; pc < 8; ++pc)
            w[pc] = tw4[l * 2048 + pc * 256 + t];
        layer_compute(v, w, 3 - l);
    }

    // ---- Transpose A->B
    #pragma unroll
    for (int r = 0; r < ROWS; ++r) {
        #pragma unroll
        for (int a = 0; a < 16; ++a)
            lds[a * PAD_STRIDE + t] = v[r][a];      // stride-1: conflict-free
        __syncthreads();
        #pragma unroll
        for (int b = 0; b < 16; ++b)                // 2-way conflict (free)
            v[r][b] = lds[thi * PAD_STRIDE + b * 16 + tlo];
        __syncthreads();
    }

    // ---- Stage B: layers 4..7 (pair dim = b); coalesced permuted twiddles
    #pragma unroll
    for (int l = 4; l < 8; ++l) {
        float4 w[8];
        #pragma unroll
        for (int pc = 0; pc < 8; ++pc)
            w[pc] = nws[(l - 4) * 2048 + pc * 256 + t];
        layer_compute(v, w, 3 - (l - 4));
    }

    // ---- Transpose B->C: thread becomes (a=thi,b=tlo) holding contiguous c
    #pragma unroll
    for (int r = 0; r < ROWS; ++r) {
        #pragma unroll
        for (int b = 0; b < 16; ++b)                // 2-way conflict (free)
            lds[thi * PAD_STRIDE + b * 16 + tlo] = v[r][b];
        __syncthreads();
        const float* bp = &lds[thi * PAD_STRIDE + tlo * 16];
        #pragma unroll
        for (int q = 0; q < 4; ++q) {               // contiguous b128 reads
            v4f c4 = *(const v4f*)(bp + 4 * q);
            v[r][4 * q + 0] = c4.x;
            v[r][4 * q + 1] = c4.y;
            v[r][4 * q + 2] = c4.z;
            v[r][4 * q + 3] = c4.w;
        }
        if (r != ROWS - 1) __syncthreads();
    }

    // ---- Stage C: layers 8..11 (pair dim = c); coalesced permuted twiddles
    #pragma unroll
    for (int l = 8; l < 12; ++l) {
        float4 w[8];
        #pragma unroll
        for (int pc = 0; pc < 8; ++pc)
            w[pc] = nws[(l - 4) * 2048 + pc * 256 + t];
        layer_compute(v, w, 3 - (l - 8));
    }

    // ---- Store via LDS restage: pack each row into flat LDS, then read back
    // lane-contiguous and store 1KB/wave contiguous. Direct stores from the
    // C-layout put each lane's 16B in its own 64B sector (64 requests/instr) —
    // the other half of the request-rate wall. Full-sector coalesced stores are
    // safe to mark nontemporal (R2's nt disaster was partial-sector writes).
    v4f* lf = (v4f*)lds;
    #pragma unroll
    for (int r = 0; r < ROWS; ++r) {
        __syncthreads();          // buffer free (prev row reads / BC transpose)
        #pragma unroll
        for (int q = 0; q < 4; ++q) {
            v4f s4;
            s4.x = v[r][4 * q + 0];
            s4.y = v[r][4 * q + 1];
            s4.z = v[r][4 * q + 2];
            s4.w = v[r][4 * q + 3];
            lf[4 * t + q] = s4;   // ds_write_b128
        }
        __syncthreads();
        float* orow = out + (size_t)(row0 + r) * N;
        #pragma unroll
        for (int k = 0; k < 4; ++k) {
            v4f s4 = lf[k * 256 + t];                          // ds_read_b128
            __builtin_nontemporal_store(s4, (v4f*)orow + k * 256 + t);
        }
    }
}

// ---- Fallback (R6 structure) if workspace is too small for the prepass
__global__ __launch_bounds__(256, 3)
void butterfly_kernel_fb(const float* __restrict__ x,
                         const float* __restrict__ tw,
                         float* __restrict__ out) {
    __shared__ float lds[BUF_WORDS];
    const int t   = threadIdx.x;
    const int thi = t >> 4;
    const int tlo = t & 15;
    const int row0 = blockIdx.x * ROWS;
    const float4* tw4 = (const float4*)tw;
    float v[ROWS][16];
    #pragma unroll
    for (int r = 0; r < ROWS; ++r) {
        const float* xr = x + (size_t)(row0 + r) * N + t;
        #pragma unroll
        for (int a = 0; a < 16; ++a)
            v[r][a] = __builtin_nontemporal_load(xr + a * 256);
    }
    #pragma unroll
    for (int l = 0; l < 4; ++l) {
        float4 w[8];
        #pragma unroll
        for (int pc = 0; pc < 8; ++pc) w[pc] = tw4[l * 2048 + pc * 256 + t];
        layer_compute(v, w, 3 - l);
    }
    #pragma unroll
    for (int r = 0; r < ROWS; ++r) {
        #pragma unroll
        for (int a = 0; a < 16; ++a) lds[a * PAD_STRIDE + t] = v[r][a];
        __syncthreads();
        #pragma unroll
        for (int b = 0; b < 16; ++b) v[r][b] = lds[thi * PAD_STRIDE + b * 16 + tlo];
        __syncthreads();
    }
    #pragma unroll
    for (int l = 4; l < 8; ++l) {
        float4 w[8];
        #pragma unroll
        for (int pc = 0; pc < 8; ++pc) w[pc] = tw4[l * 2048 + thi * 128 + pc * 16 + tlo];
        layer_compute(v, w, 3 - (l - 4));
    }
    #pragma unroll
    for (int r = 0; r < ROWS; ++r) {
        #pragma unroll
        for (int b = 0; b < 16; ++b) lds[thi * PAD_STRIDE + b * 16 + tlo] = v[r][b];
        __syncthreads();
        const float* bp = &lds[thi * PAD_STRIDE + tlo * 16];
        #pragma unroll
        for (int q = 0; q < 4; ++q) {
            v4f c4 = *(const v4f*)(bp + 4 * q);
            v[r][4 * q + 0] = c4.x; v[r][4 * q + 1] = c4.y;
            v[r][4 * q + 2] = c4.z; v[r][4 * q + 3] = c4.w;
        }
        if (r != ROWS - 1) __syncthreads();
    }
    #pragma unroll
    for (int l = 8; l < 12; ++l) {
        float4 w[8];
        #pragma unroll
        for (int pc = 0; pc < 8; ++pc) w[pc] = tw4[l * 2048 + thi * 128 + tlo * 8 + pc];
        layer_compute(v, w, 3 - (l - 8));
    }
    #pragma unroll
    for (int r = 0; r < ROWS; ++r) {
        float* orow = out + (size_t)(row0 + r) * N + 16 * t;
        #pragma unroll
        for (int q = 0; q < 4; ++q) {
            v4f s4;
            s4.x = v[r][4 * q + 0]; s4.y = v[r][4 * q + 1];
            s4.z = v[r][4 * q + 2]; s4.w = v[r][4 * q + 3];
            *(v4f*)(orow + 4 * q) = s4;
        }
    }
}

extern "C" void kernel_launch(void* const* d_in, const int* in_sizes, int n_in,
                              void* d_out, int out_size, void* d_ws, size_t ws_size,
                              hipStream_t stream) {
    const float* x  = (const float*)d_in[0];
    const float* tw = (const float*)d_in[1];
    float* out      = (float*)d_out;
    dim3 block(256);
    if (ws_size >= 8u * 2048u * 16u) {
        float4* nws = (float4*)d_ws;
        hipLaunchKernelGGL(permute_tw_kernel, dim3(64), block, 0, stream, tw, nws);
        hipLaunchKernelGGL(butterfly_kernel, dim3(BATCH / ROWS), block, 0, stream,
                           x, tw, nws, out);
    } else {
        hipLaunchKernelGGL(butterfly_kernel_fb, dim3(BATCH / ROWS), block, 0, stream,
                           x, tw, out);
    }
}